// Round 13
// baseline (96.091 us; speedup 1.0000x reference)
//
#include <hip/hip_runtime.h>
#include <math.h>

#define NN 9216           // 96*96
#define LOG2E 1.4426950408889634f

typedef __attribute__((ext_vector_type(8))) __bf16 bf16x8;
typedef __attribute__((ext_vector_type(16))) float f32x16;
typedef __attribute__((ext_vector_type(4))) unsigned int u32x4;

#define MFMA32(a,b,c) __builtin_amdgcn_mfma_f32_32x32x16_bf16(a,b,c,0,0,0)

#if __has_builtin(__builtin_amdgcn_exp2f)
#define EXP2(x) __builtin_amdgcn_exp2f(x)
#else
#define EXP2(x) exp2f(x)
#endif

__device__ __forceinline__ bf16x8 zero8() {
    bf16x8 z;
    #pragma unroll
    for (int i = 0; i < 8; i++) z[i] = (__bf16)0.0f;
    return z;
}

// single-instruction packed f32->bf16x2 (no builtin on gfx950; T12 recipe)
__device__ __forceinline__ unsigned int cvtpk(float lo, float hi) {
    unsigned int r;
    asm("v_cvt_pk_bf16_f32 %0, %1, %2" : "=v"(r) : "v"(lo), "v"(hi));
    return r;
}

__device__ __forceinline__ void plane_swap(unsigned int &a, unsigned int &b) {
    asm("v_permlane32_swap_b32 %0, %1" : "+v"(a), "+v"(b));
}

__device__ __forceinline__ void cp16(void* lds, const void* g) {
    __builtin_amdgcn_global_load_lds(
        (const __attribute__((address_space(1))) unsigned int*)g,
        (__attribute__((address_space(3))) unsigned int*)lds, 16, 0, 0);
}

// Workspace layout (bytes):
#define OFF_QB 0              // [B][N][8]  bf16 (Q pre-scaled by log2e)
#define OFF_KB 294912         // [B][N][8]  bf16
#define OFF_VB 589824         // [B][64][N] bf16 (raw V, unfolded)
#define OFF_VF 2949120        // [B][144 tiles][8 chunks][64 lanes][8] bf16, fragment-ordered folded V
#define OFF_DP 5308416        // [4z][2b][N] fp32 D-partials (dead after foldvf; aliased by parts)
#define OFF_PARTS 5308416     // [nsl][B][64][N] bf16 PV partials
#define WS_NEED12 33619968ULL // 12 slices
#define WS_NEED16 43057152ULL // 16 slices

// ---------------- Kernel 1: QKV projections ----------------
// grid (36, 2, 9), block 256. z==0: Q,K. z=1..8: V channels (z-1)*8..+8.
// x is L3-resident (9.4 MB) so the 9x re-read is cheap (R9 vs R11 evidence).
__global__ __launch_bounds__(256) void qkv_kernel(
    const float* __restrict__ x,
    const float* __restrict__ Wq, const float* __restrict__ bq,
    const float* __restrict__ Wk, const float* __restrict__ bk,
    const float* __restrict__ Wv, const float* __restrict__ bv,
    __bf16* __restrict__ QB, __bf16* __restrict__ KB, __bf16* __restrict__ VB)
{
    __shared__ float wsh[1024], bsh[16];
    int tid = threadIdx.x;
    int z = blockIdx.z, b = blockIdx.y;
    if (z == 0) {
        for (int i = tid; i < 512; i += 256) { wsh[i] = Wq[i]; wsh[512+i] = Wk[i]; }
        if (tid < 8)  { bsh[tid] = bq[tid]; bsh[8+tid] = bk[tid]; }
    } else {
        for (int i = tid; i < 512; i += 256) wsh[i] = Wv[(z-1)*512 + i];
        if (tid < 8)  bsh[tid] = bv[(z-1)*8 + tid];
    }
    __syncthreads();

    int n = blockIdx.x * 256 + tid;

    float xc[64];
    #pragma unroll
    for (int c = 0; c < 64; c++) xc[c] = x[((size_t)(b*64 + c))*NN + n];

    if (z == 0) {
        float q[8], k[8];
        #pragma unroll
        for (int o = 0; o < 8; o++) { q[o] = bsh[o]; k[o] = bsh[8+o]; }
        #pragma unroll
        for (int c = 0; c < 64; c++) {
            float xv = xc[c];
            #pragma unroll
            for (int o = 0; o < 8; o++) {
                q[o] = fmaf(wsh[o*64+c], xv, q[o]);
                k[o] = fmaf(wsh[512+o*64+c], xv, k[o]);
            }
        }
        bf16x8 qv, kv;
        #pragma unroll
        for (int o = 0; o < 8; o++) {
            qv[o] = (__bf16)(q[o] * LOG2E);   // fold log2e: exp(E)=exp2(E')
            kv[o] = (__bf16)k[o];
        }
        *(bf16x8*)(QB + ((size_t)b*NN + n)*8) = qv;
        *(bf16x8*)(KB + ((size_t)b*NN + n)*8) = kv;
    } else {
        float v[8];
        #pragma unroll
        for (int o = 0; o < 8; o++) v[o] = bsh[o];
        #pragma unroll
        for (int c = 0; c < 64; c++) {
            float xv = xc[c];
            #pragma unroll
            for (int o = 0; o < 8; o++) v[o] = fmaf(wsh[o*64+c], xv, v[o]);
        }
        #pragma unroll
        for (int o = 0; o < 8; o++)
            VB[((size_t)(b*64 + (z-1)*8 + o))*NN + n] = (__bf16)v[o];
    }
}

// ---------------- Kernel 2: D-partials via 32x32x16 MFMA ----------------
// grid (288, 2, 4), block 256 (4 waves). Block owns 32 n; z+wave split m 16 ways.
__global__ __launch_bounds__(256) void stats_kernel(
    const __bf16* __restrict__ QB, const __bf16* __restrict__ KB,
    float* __restrict__ Dp)
{
    __shared__ float Dl[4][32];
    int tid = threadIdx.x;
    int lane = tid & 63, w = tid >> 6;
    int l31 = lane & 31, h = lane >> 5;
    int b = blockIdx.y, z = blockIdx.z;
    int n0 = blockIdx.x * 32;

    f32x16 Z16;
    #pragma unroll
    for (int r = 0; r < 16; r++) Z16[r] = 0.0f;

    bf16x8 kf = zero8();
    if (lane < 32)
        kf = *(const bf16x8*)(KB + ((size_t)b*NN + n0 + l31)*8);

    float Dacc[16];
    #pragma unroll
    for (int r = 0; r < 16; r++) Dacc[r] = 0.0f;

    const __bf16* Qb = QB + (size_t)b*NN*8;
    int mbase = z*2304 + w*576;
    for (int it = 0; it < 18; it++) {
        bf16x8 qf = zero8();
        if (lane < 32)
            qf = *(const bf16x8*)(Qb + (size_t)(mbase + it*32 + l31)*8);
        f32x16 e = MFMA32(kf, qf, Z16);
        #pragma unroll
        for (int r = 0; r < 16; r++) Dacc[r] += EXP2(e[r]);
    }
    #pragma unroll
    for (int r = 0; r < 16; r++) {
        #pragma unroll
        for (int mask = 1; mask < 32; mask <<= 1)
            Dacc[r] += __shfl_xor(Dacc[r], mask);
    }
    if (l31 == 0) {
        #pragma unroll
        for (int r = 0; r < 16; r++)
            Dl[w][(r&3) + 8*(r>>2) + 4*h] = Dacc[r];
    }
    __syncthreads();
    if (tid < 32)
        Dp[((size_t)(z*2 + b))*NN + n0 + tid] =
            Dl[0][tid] + Dl[1][tid] + Dl[2][tid] + Dl[3][tid];
}

// ---------------- Kernel 3: build fragment-ordered folded VF ----------------
// grid (144, 2), block 256. Tile tg = 64 n. chunk = nt*4+ks*2+ct.
__global__ __launch_bounds__(256) void foldvf_kernel(
    const float* __restrict__ Dp, const float* __restrict__ gamma_p,
    const __bf16* __restrict__ VB, __bf16* __restrict__ VF)
{
    __shared__ float Rl[64];
    int tid = threadIdx.x;
    int b = blockIdx.y, tg = blockIdx.x;
    int n0 = tg * 64;
    if (tid < 64) {
        float d = 0.0f;
        #pragma unroll
        for (int zz = 0; zz < 4; zz++)
            d += Dp[((size_t)(zz*2 + b))*NN + n0 + tid];
        Rl[tid] = gamma_p[0] / d;
    }
    __syncthreads();

    #pragma unroll
    for (int i = 0; i < 2; i++) {
        int p = tid + i*256;               // 0..511
        int chunk = p >> 6, lane = p & 63;
        int c  = (chunk & 1)*32 + (lane & 31);
        int nl = ((chunk >> 2) & 1)*32 + ((chunk >> 1) & 1)*16 + (lane >> 5)*8;
        bf16x8 v = *(const bf16x8*)(VB + ((size_t)(b*64 + c))*NN + n0 + nl);
        bf16x8 ov;
        #pragma unroll
        for (int j = 0; j < 8; j++)
            ov[j] = (__bf16)((float)v[j] * Rl[nl + j]);
        *(bf16x8*)(VF + (((size_t)(b*144 + tg))*8 + chunk)*512 + lane*8) = ov;
    }
}

// ---------------- Kernel 4: out = x (atomic-fallback path only) ----------------
__global__ __launch_bounds__(256) void init_kernel(
    const float* __restrict__ x, float* __restrict__ out)
{
    int i = blockIdx.x*256 + threadIdx.x;
    ((float4*)out)[i] = ((const float4*)x)[i];
}

// ---------------- Kernel 5: fused exp2(E') + PV ----------------
// grid (72, 2, Z), block 256 (4 waves). Block: 128 m; wave: 32 m.
// Split z: ntiles = 144/Z tiles of 64 n each. bf16 partial stores.
__global__ __launch_bounds__(256) void pv_kernel(
    const __bf16* __restrict__ QB, const __bf16* __restrict__ KB,
    const __bf16* __restrict__ VF, float* __restrict__ out,
    __bf16* __restrict__ parts, int ntiles)
{
    __shared__ __bf16 vbuf[2][4096];   // 2 x 8KB fragment-ordered V tile
    __shared__ __bf16 klin[2][512];    // 2 x 1KB K tile

    int tid = threadIdx.x;
    int lane = tid & 63, w = tid >> 6;
    int l31 = lane & 31, h = lane >> 5;
    int b = blockIdx.y, s = blockIdx.z;
    int mw = blockIdx.x * 128 + w * 32;

    f32x16 Z16;
    #pragma unroll
    for (int r = 0; r < 16; r++) Z16[r] = 0.0f;

    bf16x8 qf = zero8();
    if (lane < 32)
        qf = *(const bf16x8*)(QB + ((size_t)b*NN + mw + l31)*8);

    f32x16 acc[2];
    acc[0] = Z16; acc[1] = Z16;

    const __bf16* kbase = KB + ((size_t)b*NN + s*ntiles*64)*8;      // + t*512 + row*8
    const __bf16* vbase = VF + ((size_t)(b*144 + s*ntiles))*8*512;  // + t*4096 elements

// Linear both sides: thread p copies VF chunk-slot p (16B) to LDS offset p*16.
#define STAGE(bi, stq) do {                                                   \
    const __bf16* tile_ = vbase + (size_t)(stq)*4096;                         \
    cp16((char*)vbuf[bi] + w*1024,        tile_ + (w*64 + lane)*8);           \
    cp16((char*)vbuf[bi] + 4096 + w*1024, tile_ + (256 + w*64 + lane)*8);     \
    if (w == 0)                                                               \
        cp16((char*)klin[bi], kbase + ((size_t)(stq)*64 + lane)*8);           \
} while (0)

    STAGE(0, 0);

    for (int t = 0; t < ntiles; t++) {
        int bi = t & 1;
        __syncthreads();                  // stage(t) complete; buf[bi^1] free
        if (t < ntiles - 1) {
            if (bi == 0) STAGE(1, t+1); else STAGE(0, t+1);
        }

        // QK: K fragments from LDS (half-wave b128 reads, conflict-free)
        bf16x8 kfr0 = zero8(), kfr1 = zero8();
        if (lane < 32) {
            kfr0 = *(const bf16x8*)(klin[bi] + l31*8);
            kfr1 = *(const bf16x8*)(klin[bi] + (32 + l31)*8);
        }
        f32x16 e0 = MFMA32(kfr0, qf, Z16);
        f32x16 e1 = MFMA32(kfr1, qf, Z16);

        // exp + pack into PV A-fragments (in-register, T12; single-instr cvt_pk)
        bf16x8 pa[2][2];
        #pragma unroll
        for (int nt = 0; nt < 2; nt++) {
            const f32x16& e = nt ? e1 : e0;
            float pf[16];
            #pragma unroll
            for (int r = 0; r < 16; r++) pf[r] = EXP2(e[r]);
            unsigned int u[8];
            #pragma unroll
            for (int q = 0; q < 8; q++) u[q] = cvtpk(pf[2*q], pf[2*q+1]);
            plane_swap(u[0], u[2]); plane_swap(u[1], u[3]);
            plane_swap(u[4], u[6]); plane_swap(u[5], u[7]);
            u32x4 t0 = {u[0], u[1], u[2], u[3]};
            u32x4 t1 = {u[4], u[5], u[6], u[7]};
            pa[nt][0] = __builtin_bit_cast(bf16x8, t0);
            pa[nt][1] = __builtin_bit_cast(bf16x8, t1);
        }

        // PV cluster: chunk = nt*4 + ks*2 + ct; B-frag = ds_read_b128 at chunk*1KB + lane*16
        __builtin_amdgcn_s_setprio(1);
        #pragma unroll
        for (int chunk = 0; chunk < 8; chunk++) {
            bf16x8 bfr = *(const bf16x8*)((char*)vbuf[bi] + chunk*1024 + lane*16);
            acc[chunk & 1] = MFMA32(pa[chunk >> 2][(chunk >> 1) & 1], bfr, acc[chunk & 1]);
        }
        __builtin_amdgcn_s_setprio(0);
    }

    if (parts != nullptr) {
        __bf16* pp = parts + ((size_t)(s*2 + b))*64*NN;
        #pragma unroll
        for (int ct = 0; ct < 2; ct++) {
            int c = ct*32 + l31;
            __bf16* row = pp + (size_t)c*NN + mw + 4*h;
            #pragma unroll
            for (int q = 0; q < 4; q++) {
                uint2 v2;
                v2.x = cvtpk(acc[ct][4*q],   acc[ct][4*q+1]);
                v2.y = cvtpk(acc[ct][4*q+2], acc[ct][4*q+3]);
                *(uint2*)(row + q*8) = v2;
            }
        }
    } else {
        #pragma unroll
        for (int ct = 0; ct < 2; ct++) {
            int c = ct*32 + l31;
            #pragma unroll
            for (int r = 0; r < 16; r++) {
                int m = mw + (r&3) + 8*(r>>2) + 4*h;
                atomicAdd(out + ((size_t)(b*64 + c))*NN + m, (float)acc[ct][r]);
            }
        }
    }
}

// ---------------- Kernel 6: out = x + sum_s parts[s] ----------------
// grid 576, block 256; thread owns 8 consecutive floats (576*256*8 = 1179648 = out_size).
__global__ __launch_bounds__(256) void reduce_kernel(
    const float* __restrict__ x, const __bf16* __restrict__ parts,
    float* __restrict__ out, int nsl)
{
    size_t f0 = ((size_t)blockIdx.x*256 + threadIdx.x) * 8;
    float o[8];
    float4 a = *(const float4*)(x + f0);
    float4 c = *(const float4*)(x + f0 + 4);
    o[0]=a.x; o[1]=a.y; o[2]=a.z; o[3]=a.w;
    o[4]=c.x; o[5]=c.y; o[6]=c.z; o[7]=c.w;
    #pragma unroll 4
    for (int sIdx = 0; sIdx < nsl; sIdx++) {
        bf16x8 p = *(const bf16x8*)(parts + (size_t)sIdx*(128*NN) + f0);
        #pragma unroll
        for (int j = 0; j < 8; j++) o[j] += (float)p[j];
    }
    float4 r0 = make_float4(o[0],o[1],o[2],o[3]);
    float4 r1 = make_float4(o[4],o[5],o[6],o[7]);
    *(float4*)(out + f0) = r0;
    *(float4*)(out + f0 + 4) = r1;
}

extern "C" void kernel_launch(void* const* d_in, const int* in_sizes, int n_in,
                              void* d_out, int out_size, void* d_ws, size_t ws_size,
                              hipStream_t stream) {
    const float* x     = (const float*)d_in[0];
    const float* Wq    = (const float*)d_in[1];
    const float* bq    = (const float*)d_in[2];
    const float* Wk    = (const float*)d_in[3];
    const float* bk    = (const float*)d_in[4];
    const float* Wv    = (const float*)d_in[5];
    const float* bv    = (const float*)d_in[6];
    const float* gamma = (const float*)d_in[7];
    float* out = (float*)d_out;
    char* ws   = (char*)d_ws;

    __bf16* QB = (__bf16*)(ws + OFF_QB);
    __bf16* KB = (__bf16*)(ws + OFF_KB);
    __bf16* VB = (__bf16*)(ws + OFF_VB);
    __bf16* VF = (__bf16*)(ws + OFF_VF);
    float*  Dp = (float*)(ws + OFF_DP);

    qkv_kernel<<<dim3(36, 2, 9), 256, 0, stream>>>(x, Wq, bq, Wk, bk, Wv, bv, QB, KB, VB);
    stats_kernel<<<dim3(288, 2, 4), 256, 0, stream>>>(QB, KB, Dp);
    foldvf_kernel<<<dim3(144, 2), 256, 0, stream>>>(Dp, gamma, VB, VF);

    if (ws_size >= WS_NEED16) {
        __bf16* parts = (__bf16*)(ws + OFF_PARTS);
        pv_kernel<<<dim3(72, 2, 16), 256, 0, stream>>>(QB, KB, VF, out, parts, 9);
        reduce_kernel<<<dim3(576), 256, 0, stream>>>(x, parts, out, 16);
    } else if (ws_size >= WS_NEED12) {
        __bf16* parts = (__bf16*)(ws + OFF_PARTS);
        pv_kernel<<<dim3(72, 2, 12), 256, 0, stream>>>(QB, KB, VF, out, parts, 12);
        reduce_kernel<<<dim3(576), 256, 0, stream>>>(x, parts, out, 12);
    } else {
        init_kernel<<<dim3(1152), 256, 0, stream>>>(x, out);
        pv_kernel<<<dim3(72, 2, 12), 256, 0, stream>>>(QB, KB, VF, out, nullptr, 12);
    }
}

// Round 14
// 90.009 us; speedup vs baseline: 1.0676x; 1.0676x over previous
//
#include <hip/hip_runtime.h>
#include <math.h>

#define NN 9216           // 96*96
#define LOG2E 1.4426950408889634f

typedef __attribute__((ext_vector_type(8))) __bf16 bf16x8;
typedef __attribute__((ext_vector_type(16))) float f32x16;
typedef __attribute__((ext_vector_type(4))) unsigned int u32x4;

#define MFMA32(a,b,c) __builtin_amdgcn_mfma_f32_32x32x16_bf16(a,b,c,0,0,0)

#if __has_builtin(__builtin_amdgcn_exp2f)
#define EXP2(x) __builtin_amdgcn_exp2f(x)
#else
#define EXP2(x) exp2f(x)
#endif

__device__ __forceinline__ bf16x8 zero8() {
    bf16x8 z;
    #pragma unroll
    for (int i = 0; i < 8; i++) z[i] = (__bf16)0.0f;
    return z;
}

// single-instruction packed f32->bf16x2 (no builtin on gfx950; T12 recipe)
__device__ __forceinline__ unsigned int cvtpk(float lo, float hi) {
    unsigned int r;
    asm("v_cvt_pk_bf16_f32 %0, %1, %2" : "=v"(r) : "v"(lo), "v"(hi));
    return r;
}

__device__ __forceinline__ void plane_swap(unsigned int &a, unsigned int &b) {
    asm("v_permlane32_swap_b32 %0, %1" : "+v"(a), "+v"(b));
}

__device__ __forceinline__ void cp16(void* lds, const void* g) {
    __builtin_amdgcn_global_load_lds(
        (const __attribute__((address_space(1))) unsigned int*)g,
        (__attribute__((address_space(3))) unsigned int*)lds, 16, 0, 0);
}

// Workspace layout (bytes):
#define OFF_QB 0              // [B][N][8]  bf16 (Q pre-scaled by log2e)
#define OFF_KB 294912         // [B][N][8]  bf16
#define OFF_VB 589824         // [B][64][N] bf16 (raw V, unfolded)
#define OFF_VF 2949120        // [B][144 tiles][8 chunks][64 lanes][8] bf16, fragment-ordered folded V
#define OFF_DP 5308416        // [4z][2b][N] fp32 D-partials (dead after foldvf; aliased by parts)
#define OFF_PARTS 5308416     // [12][B][64][N] bf16 PV partials
#define WS_NEED 33619968ULL

// ---------------- Kernel 1: QKV projections ----------------
// grid (36, 2, 9), block 256. z==0: Q,K. z=1..8: V channels (z-1)*8..+8.
// x is L3-resident (9.4 MB) so the 9x re-read is cheap (R9 vs R11 evidence).
__global__ __launch_bounds__(256) void qkv_kernel(
    const float* __restrict__ x,
    const float* __restrict__ Wq, const float* __restrict__ bq,
    const float* __restrict__ Wk, const float* __restrict__ bk,
    const float* __restrict__ Wv, const float* __restrict__ bv,
    __bf16* __restrict__ QB, __bf16* __restrict__ KB, __bf16* __restrict__ VB)
{
    __shared__ float wsh[1024], bsh[16];
    int tid = threadIdx.x;
    int z = blockIdx.z, b = blockIdx.y;
    if (z == 0) {
        for (int i = tid; i < 512; i += 256) { wsh[i] = Wq[i]; wsh[512+i] = Wk[i]; }
        if (tid < 8)  { bsh[tid] = bq[tid]; bsh[8+tid] = bk[tid]; }
    } else {
        for (int i = tid; i < 512; i += 256) wsh[i] = Wv[(z-1)*512 + i];
        if (tid < 8)  bsh[tid] = bv[(z-1)*8 + tid];
    }
    __syncthreads();

    int n = blockIdx.x * 256 + tid;

    float xc[64];
    #pragma unroll
    for (int c = 0; c < 64; c++) xc[c] = x[((size_t)(b*64 + c))*NN + n];

    if (z == 0) {
        float q[8], k[8];
        #pragma unroll
        for (int o = 0; o < 8; o++) { q[o] = bsh[o]; k[o] = bsh[8+o]; }
        #pragma unroll
        for (int c = 0; c < 64; c++) {
            float xv = xc[c];
            #pragma unroll
            for (int o = 0; o < 8; o++) {
                q[o] = fmaf(wsh[o*64+c], xv, q[o]);
                k[o] = fmaf(wsh[512+o*64+c], xv, k[o]);
            }
        }
        bf16x8 qv, kv;
        #pragma unroll
        for (int o = 0; o < 8; o++) {
            qv[o] = (__bf16)(q[o] * LOG2E);   // fold log2e: exp(E)=exp2(E')
            kv[o] = (__bf16)k[o];
        }
        *(bf16x8*)(QB + ((size_t)b*NN + n)*8) = qv;
        *(bf16x8*)(KB + ((size_t)b*NN + n)*8) = kv;
    } else {
        float v[8];
        #pragma unroll
        for (int o = 0; o < 8; o++) v[o] = bsh[o];
        #pragma unroll
        for (int c = 0; c < 64; c++) {
            float xv = xc[c];
            #pragma unroll
            for (int o = 0; o < 8; o++) v[o] = fmaf(wsh[o*64+c], xv, v[o]);
        }
        #pragma unroll
        for (int o = 0; o < 8; o++)
            VB[((size_t)(b*64 + (z-1)*8 + o))*NN + n] = (__bf16)v[o];
    }
}

// ---------------- Kernel 2: D-partials via 32x32x16 MFMA ----------------
// grid (288, 2, 4), block 256 (4 waves). Block owns 32 n; z+wave split m 16 ways.
// unroll 2: two independent QK->exp chains in flight (no in-loop barrier).
__global__ __launch_bounds__(256) void stats_kernel(
    const __bf16* __restrict__ QB, const __bf16* __restrict__ KB,
    float* __restrict__ Dp)
{
    __shared__ float Dl[4][32];
    int tid = threadIdx.x;
    int lane = tid & 63, w = tid >> 6;
    int l31 = lane & 31, h = lane >> 5;
    int b = blockIdx.y, z = blockIdx.z;
    int n0 = blockIdx.x * 32;

    f32x16 Z16;
    #pragma unroll
    for (int r = 0; r < 16; r++) Z16[r] = 0.0f;

    bf16x8 kf = zero8();
    if (lane < 32)
        kf = *(const bf16x8*)(KB + ((size_t)b*NN + n0 + l31)*8);

    float Dacc[16];
    #pragma unroll
    for (int r = 0; r < 16; r++) Dacc[r] = 0.0f;

    const __bf16* Qb = QB + (size_t)b*NN*8;
    int mbase = z*2304 + w*576;
    #pragma unroll 2
    for (int it = 0; it < 18; it++) {
        bf16x8 qf = zero8();
        if (lane < 32)
            qf = *(const bf16x8*)(Qb + (size_t)(mbase + it*32 + l31)*8);
        f32x16 e = MFMA32(kf, qf, Z16);
        #pragma unroll
        for (int r = 0; r < 16; r++) Dacc[r] += EXP2(e[r]);
    }
    #pragma unroll
    for (int r = 0; r < 16; r++) {
        #pragma unroll
        for (int mask = 1; mask < 32; mask <<= 1)
            Dacc[r] += __shfl_xor(Dacc[r], mask);
    }
    if (l31 == 0) {
        #pragma unroll
        for (int r = 0; r < 16; r++)
            Dl[w][(r&3) + 8*(r>>2) + 4*h] = Dacc[r];
    }
    __syncthreads();
    if (tid < 32)
        Dp[((size_t)(z*2 + b))*NN + n0 + tid] =
            Dl[0][tid] + Dl[1][tid] + Dl[2][tid] + Dl[3][tid];
}

// ---------------- Kernel 3: build fragment-ordered folded VF ----------------
// grid (144, 2), block 256. Tile tg = 64 n. chunk = nt*4+ks*2+ct.
__global__ __launch_bounds__(256) void foldvf_kernel(
    const float* __restrict__ Dp, const float* __restrict__ gamma_p,
    const __bf16* __restrict__ VB, __bf16* __restrict__ VF)
{
    __shared__ float Rl[64];
    int tid = threadIdx.x;
    int b = blockIdx.y, tg = blockIdx.x;
    int n0 = tg * 64;
    if (tid < 64) {
        float d = 0.0f;
        #pragma unroll
        for (int zz = 0; zz < 4; zz++)
            d += Dp[((size_t)(zz*2 + b))*NN + n0 + tid];
        Rl[tid] = gamma_p[0] / d;
    }
    __syncthreads();

    #pragma unroll
    for (int i = 0; i < 2; i++) {
        int p = tid + i*256;               // 0..511
        int chunk = p >> 6, lane = p & 63;
        int c  = (chunk & 1)*32 + (lane & 31);
        int nl = ((chunk >> 2) & 1)*32 + ((chunk >> 1) & 1)*16 + (lane >> 5)*8;
        bf16x8 v = *(const bf16x8*)(VB + ((size_t)(b*64 + c))*NN + n0 + nl);
        bf16x8 ov;
        #pragma unroll
        for (int j = 0; j < 8; j++)
            ov[j] = (__bf16)((float)v[j] * Rl[nl + j]);
        *(bf16x8*)(VF + (((size_t)(b*144 + tg))*8 + chunk)*512 + lane*8) = ov;
    }
}

// ---------------- Kernel 4: out = x (atomic-fallback path only) ----------------
__global__ __launch_bounds__(256) void init_kernel(
    const float* __restrict__ x, float* __restrict__ out)
{
    int i = blockIdx.x*256 + threadIdx.x;
    ((float4*)out)[i] = ((const float4*)x)[i];
}

// ---------------- Kernel 5: fused exp2(E') + PV (R12 structure, compile-time 12) ----------------
// grid (72, 2, 12), block 256 (4 waves). Block: 128 m; wave: 32 m.
// Split z: 768 n, 12 tiles of 64. bf16 partial stores.
__global__ __launch_bounds__(256) void pv_kernel(
    const __bf16* __restrict__ QB, const __bf16* __restrict__ KB,
    const __bf16* __restrict__ VF, float* __restrict__ out,
    __bf16* __restrict__ parts)
{
    __shared__ __bf16 vbuf[2][4096];   // 2 x 8KB fragment-ordered V tile
    __shared__ __bf16 klin[2][512];    // 2 x 1KB K tile

    int tid = threadIdx.x;
    int lane = tid & 63, w = tid >> 6;
    int l31 = lane & 31, h = lane >> 5;
    int b = blockIdx.y, s = blockIdx.z;
    int mw = blockIdx.x * 128 + w * 32;

    f32x16 Z16;
    #pragma unroll
    for (int r = 0; r < 16; r++) Z16[r] = 0.0f;

    bf16x8 qf = zero8();
    if (lane < 32)
        qf = *(const bf16x8*)(QB + ((size_t)b*NN + mw + l31)*8);

    f32x16 acc[2];
    acc[0] = Z16; acc[1] = Z16;

    const __bf16* kbase = KB + ((size_t)b*NN + s*768)*8;        // + t*512 + row*8
    const __bf16* vbase = VF + ((size_t)(b*144 + s*12))*8*512;  // + t*4096 elements

// Linear both sides: thread p copies VF chunk-slot p (16B) to LDS offset p*16.
#define STAGE(bi, stq) do {                                                   \
    const __bf16* tile_ = vbase + (size_t)(stq)*4096;                         \
    cp16((char*)vbuf[bi] + w*1024,        tile_ + (w*64 + lane)*8);           \
    cp16((char*)vbuf[bi] + 4096 + w*1024, tile_ + (256 + w*64 + lane)*8);     \
    if (w == 0)                                                               \
        cp16((char*)klin[bi], kbase + ((size_t)(stq)*64 + lane)*8);           \
} while (0)

    STAGE(0, 0);

    for (int t = 0; t < 12; t++) {
        int bi = t & 1;
        __syncthreads();                  // stage(t) complete; buf[bi^1] free
        if (t < 11) {
            if (bi == 0) STAGE(1, t+1); else STAGE(0, t+1);
        }

        // QK: K fragments from LDS (half-wave b128 reads, conflict-free)
        bf16x8 kfr0 = zero8(), kfr1 = zero8();
        if (lane < 32) {
            kfr0 = *(const bf16x8*)(klin[bi] + l31*8);
            kfr1 = *(const bf16x8*)(klin[bi] + (32 + l31)*8);
        }
        f32x16 e0 = MFMA32(kfr0, qf, Z16);
        f32x16 e1 = MFMA32(kfr1, qf, Z16);

        // exp + pack into PV A-fragments (in-register, T12; single-instr cvt_pk)
        bf16x8 pa[2][2];
        #pragma unroll
        for (int nt = 0; nt < 2; nt++) {
            const f32x16& e = nt ? e1 : e0;
            float pf[16];
            #pragma unroll
            for (int r = 0; r < 16; r++) pf[r] = EXP2(e[r]);
            unsigned int u[8];
            #pragma unroll
            for (int q = 0; q < 8; q++) u[q] = cvtpk(pf[2*q], pf[2*q+1]);
            plane_swap(u[0], u[2]); plane_swap(u[1], u[3]);
            plane_swap(u[4], u[6]); plane_swap(u[5], u[7]);
            u32x4 t0 = {u[0], u[1], u[2], u[3]};
            u32x4 t1 = {u[4], u[5], u[6], u[7]};
            pa[nt][0] = __builtin_bit_cast(bf16x8, t0);
            pa[nt][1] = __builtin_bit_cast(bf16x8, t1);
        }

        // PV cluster: chunk = nt*4 + ks*2 + ct; B-frag = ds_read_b128 at chunk*1KB + lane*16
        __builtin_amdgcn_s_setprio(1);
        #pragma unroll
        for (int chunk = 0; chunk < 8; chunk++) {
            bf16x8 bfr = *(const bf16x8*)((char*)vbuf[bi] + chunk*1024 + lane*16);
            acc[chunk & 1] = MFMA32(pa[chunk >> 2][(chunk >> 1) & 1], bfr, acc[chunk & 1]);
        }
        __builtin_amdgcn_s_setprio(0);
    }

    if (parts != nullptr) {
        __bf16* pp = parts + ((size_t)(s*2 + b))*64*NN;
        #pragma unroll
        for (int ct = 0; ct < 2; ct++) {
            int c = ct*32 + l31;
            __bf16* row = pp + (size_t)c*NN + mw + 4*h;
            #pragma unroll
            for (int q = 0; q < 4; q++) {
                uint2 v2;
                v2.x = cvtpk(acc[ct][4*q],   acc[ct][4*q+1]);
                v2.y = cvtpk(acc[ct][4*q+2], acc[ct][4*q+3]);
                *(uint2*)(row + q*8) = v2;
            }
        }
    } else {
        #pragma unroll
        for (int ct = 0; ct < 2; ct++) {
            int c = ct*32 + l31;
            #pragma unroll
            for (int r = 0; r < 16; r++) {
                int m = mw + (r&3) + 8*(r>>2) + 4*h;
                atomicAdd(out + ((size_t)(b*64 + c))*NN + m, (float)acc[ct][r]);
            }
        }
    }
}

// ---------------- Kernel 6: out = x + sum_s parts[s] ----------------
// grid 576, block 256; thread owns 8 consecutive floats (576*256*8 = 1179648 = out_size).
__global__ __launch_bounds__(256) void reduce_kernel(
    const float* __restrict__ x, const __bf16* __restrict__ parts,
    float* __restrict__ out)
{
    size_t f0 = ((size_t)blockIdx.x*256 + threadIdx.x) * 8;
    float o[8];
    float4 a = *(const float4*)(x + f0);
    float4 c = *(const float4*)(x + f0 + 4);
    o[0]=a.x; o[1]=a.y; o[2]=a.z; o[3]=a.w;
    o[4]=c.x; o[5]=c.y; o[6]=c.z; o[7]=c.w;
    #pragma unroll
    for (int sIdx = 0; sIdx < 12; sIdx++) {
        bf16x8 p = *(const bf16x8*)(parts + (size_t)sIdx*(128*NN) + f0);
        #pragma unroll
        for (int j = 0; j < 8; j++) o[j] += (float)p[j];
    }
    float4 r0 = make_float4(o[0],o[1],o[2],o[3]);
    float4 r1 = make_float4(o[4],o[5],o[6],o[7]);
    *(float4*)(out + f0) = r0;
    *(float4*)(out + f0 + 4) = r1;
}

extern "C" void kernel_launch(void* const* d_in, const int* in_sizes, int n_in,
                              void* d_out, int out_size, void* d_ws, size_t ws_size,
                              hipStream_t stream) {
    const float* x     = (const float*)d_in[0];
    const float* Wq    = (const float*)d_in[1];
    const float* bq    = (const float*)d_in[2];
    const float* Wk    = (const float*)d_in[3];
    const float* bk    = (const float*)d_in[4];
    const float* Wv    = (const float*)d_in[5];
    const float* bv    = (const float*)d_in[6];
    const float* gamma = (const float*)d_in[7];
    float* out = (float*)d_out;
    char* ws   = (char*)d_ws;

    __bf16* QB = (__bf16*)(ws + OFF_QB);
    __bf16* KB = (__bf16*)(ws + OFF_KB);
    __bf16* VB = (__bf16*)(ws + OFF_VB);
    __bf16* VF = (__bf16*)(ws + OFF_VF);
    float*  Dp = (float*)(ws + OFF_DP);

    qkv_kernel<<<dim3(36, 2, 9), 256, 0, stream>>>(x, Wq, bq, Wk, bk, Wv, bv, QB, KB, VB);
    stats_kernel<<<dim3(288, 2, 4), 256, 0, stream>>>(QB, KB, Dp);
    foldvf_kernel<<<dim3(144, 2), 256, 0, stream>>>(Dp, gamma, VB, VF);

    if (ws_size >= WS_NEED) {
        __bf16* parts = (__bf16*)(ws + OFF_PARTS);
        pv_kernel<<<dim3(72, 2, 12), 256, 0, stream>>>(QB, KB, VF, out, parts);
        reduce_kernel<<<dim3(576), 256, 0, stream>>>(x, parts, out);
    } else {
        init_kernel<<<dim3(1152), 256, 0, stream>>>(x, out);
        pv_kernel<<<dim3(72, 2, 12), 256, 0, stream>>>(QB, KB, VF, out, nullptr);
    }
}